// Round 1
// 777.769 us; speedup vs baseline: 1.2597x; 1.2597x over previous
//
#include <hip/hip_runtime.h>
#include <cstdint>

#define HH 480
#define WW 640
#define BATCH 8
#define NPIX (HH * WW)
#define TOPK 500
#define NBINS 4096
#define POOLCAP 32768
#define TS 32
#define HALO 10
#define LT 52  // TS + 2*HALO

// ---------------------------------------------------------------------------
// Fused 2-iteration modified NMS. Final mask at p depends on scores within
// radius 10, so a 32x32 tile + halo 10 reproduces the reference bit-exactly
// (max/compare only). Survivors (interior, border-clipped) are pushed to a
// per-batch candidate pool with block-aggregated atomics.
// ---------------------------------------------------------------------------
__global__ __launch_bounds__(256) void fused_nms_k(const float* __restrict__ sc,
                                                   unsigned* __restrict__ cnt,
                                                   unsigned long long* __restrict__ pool) {
    __shared__ float S[LT][LT + 1];
    __shared__ float T[LT][LT + 1];
    __shared__ float U[LT][LT + 1];
    __shared__ unsigned char M0[LT][LT];
    __shared__ unsigned char M1[LT][LT];
    __shared__ unsigned char SP[LT][LT];
    __shared__ unsigned long long lst[512];
    __shared__ unsigned lcnt, gbase;

    int bx = blockIdx.x * TS, by = blockIdx.y * TS, b = blockIdx.z;
    const float* img = sc + (size_t)b * NPIX;
    int lin = threadIdx.x;
    if (lin == 0) lcnt = 0;

    // A: load scores tile, -inf outside image (reduce_window pad semantics)
    for (int i = lin; i < LT * LT; i += 256) {
        int r = i / LT, c = i - r * LT;
        int gy = by + r - HALO, gx = bx + c - HALO;
        float v = -INFINITY;
        if (gy >= 0 && gy < HH && gx >= 0 && gx < WW) v = img[gy * WW + gx];
        S[r][c] = v;
    }
    __syncthreads();
    // B: rowmax(S) -> T, rows [0,52), cols [2,50)
    for (int i = lin; i < LT * 48; i += 256) {
        int r = i / 48, c = 2 + (i - r * 48);
        T[r][c] = fmaxf(fmaxf(fmaxf(S[r][c - 2], S[r][c - 1]),
                              fmaxf(S[r][c], S[r][c + 1])), S[r][c + 2]);
    }
    __syncthreads();
    // C: m0 = (s == maxpool(s)) at [2,50)^2 ; 0 outside image
    for (int i = lin; i < 48 * 48; i += 256) {
        int r = 2 + i / 48, c = 2 + i % 48;
        float m = fmaxf(fmaxf(fmaxf(T[r - 2][c], T[r - 1][c]),
                              fmaxf(T[r][c], T[r + 1][c])), T[r + 2][c]);
        int gy = by + r - HALO, gx = bx + c - HALO;
        bool inim = (gy >= 0 && gy < HH && gx >= 0 && gx < WW);
        M0[r][c] = (inim && S[r][c] == m) ? 1 : 0;
    }
    __syncthreads();
    // D: rowmax(M0) -> T, rows [2,50), cols [4,48)
    for (int i = lin; i < 48 * 44; i += 256) {
        int r = 2 + i / 44, c = 4 + i % 44;
        int mm = M0[r][c - 2] | M0[r][c - 1] | M0[r][c] | M0[r][c + 1] | M0[r][c + 2];
        T[r][c] = (float)mm;
    }
    __syncthreads();
    // E: supp1 at [4,48)^2 ; U = supp-scores (pad -inf outside image)
    for (int i = lin; i < 44 * 44; i += 256) {
        int r = 4 + i / 44, c = 4 + i % 44;
        float d = fmaxf(fmaxf(fmaxf(T[r - 2][c], T[r - 1][c]),
                              fmaxf(T[r][c], T[r + 1][c])), T[r + 2][c]);
        bool sp = d > 0.0f;
        SP[r][c] = sp ? 1 : 0;
        int gy = by + r - HALO, gx = bx + c - HALO;
        bool inim = (gy >= 0 && gy < HH && gx >= 0 && gx < WW);
        U[r][c] = inim ? (sp ? 0.0f : S[r][c]) : -INFINITY;
    }
    __syncthreads();
    // F: rowmax(U) -> T, rows [4,48), cols [6,46)
    for (int i = lin; i < 44 * 40; i += 256) {
        int r = 4 + i / 40, c = 6 + i % 40;
        T[r][c] = fmaxf(fmaxf(fmaxf(U[r][c - 2], U[r][c - 1]),
                              fmaxf(U[r][c], U[r][c + 1])), U[r][c + 2]);
    }
    __syncthreads();
    // G: m1 = m0 | (new_max & ~supp1) at [6,46)^2
    for (int i = lin; i < 40 * 40; i += 256) {
        int r = 6 + i / 40, c = 6 + i % 40;
        float m = fmaxf(fmaxf(fmaxf(T[r - 2][c], T[r - 1][c]),
                              fmaxf(T[r][c], T[r + 1][c])), T[r + 2][c]);
        int gy = by + r - HALO, gx = bx + c - HALO;
        bool inim = (gy >= 0 && gy < HH && gx >= 0 && gx < WW);
        bool nm = inim && !SP[r][c] && (U[r][c] == m);
        M1[r][c] = (M0[r][c] | (nm ? 1 : 0));
    }
    __syncthreads();
    // H: rowmax(M1) -> T, rows [6,46), cols [8,44)
    for (int i = lin; i < 40 * 36; i += 256) {
        int r = 6 + i / 36, c = 8 + i % 36;
        int mm = M1[r][c - 2] | M1[r][c - 1] | M1[r][c] | M1[r][c + 1] | M1[r][c + 2];
        T[r][c] = (float)mm;
    }
    __syncthreads();
    // I: supp2 at [8,44)^2 ; U = supp-scores round 2
    for (int i = lin; i < 36 * 36; i += 256) {
        int r = 8 + i / 36, c = 8 + i % 36;
        float d = fmaxf(fmaxf(fmaxf(T[r - 2][c], T[r - 1][c]),
                              fmaxf(T[r][c], T[r + 1][c])), T[r + 2][c]);
        bool sp = d > 0.0f;
        SP[r][c] = sp ? 1 : 0;
        int gy = by + r - HALO, gx = bx + c - HALO;
        bool inim = (gy >= 0 && gy < HH && gx >= 0 && gx < WW);
        U[r][c] = inim ? (sp ? 0.0f : S[r][c]) : -INFINITY;
    }
    __syncthreads();
    // J: rowmax(U) -> T, rows [8,44), cols [10,42)
    for (int i = lin; i < 36 * 32; i += 256) {
        int r = 8 + i / 32, c = 10 + (i & 31);
        T[r][c] = fmaxf(fmaxf(fmaxf(U[r][c - 2], U[r][c - 1]),
                              fmaxf(U[r][c], U[r][c + 1])), U[r][c + 2]);
    }
    __syncthreads();
    // K: final mask on interior [10,42)^2, push survivors
    for (int i = lin; i < 32 * 32; i += 256) {
        int r = 10 + (i >> 5), c = 10 + (i & 31);
        float m = fmaxf(fmaxf(fmaxf(T[r - 2][c], T[r - 1][c]),
                              fmaxf(T[r][c], T[r + 1][c])), T[r + 2][c]);
        bool nm = !SP[r][c] && (U[r][c] == m);
        bool m2 = M1[r][c] || nm;
        int gy = by + r - HALO, gx = bx + c - HALO;  // always in-image (tiles exact)
        if (m2 && gy >= 3 && gy <= HH - 3 && gx >= 3 && gx <= WW - 3) {
            unsigned pos = atomicAdd(&lcnt, 1u);
            if (pos < 512) {
                unsigned p = (unsigned)(gy * WW + gx);
                lst[pos] = ((unsigned long long)__float_as_uint(S[r][c]) << 32) |
                           (unsigned long long)(0xFFFFFFFFu - p);
            }
        }
    }
    __syncthreads();
    unsigned nl = lcnt < 512u ? lcnt : 512u;
    if (lin == 0 && nl) gbase = atomicAdd(&cnt[b], nl);
    __syncthreads();
    for (unsigned i = lin; i < nl; i += 256) {
        unsigned dst = gbase + i;
        if (dst < POOLCAP) pool[(size_t)b * POOLCAP + dst] = lst[i];
    }
}

__device__ __forceinline__ int bucket_of(float v) {
    int bk = (int)(v * 4096.0f);  // exact monotone for v in [0,1)
    return bk > 4095 ? 4095 : (bk < 0 ? 0 : bk);
}

__device__ __forceinline__ unsigned long long shfl_xor_u64(unsigned long long v, int m) {
    int lo = __shfl_xor((int)(unsigned)(v & 0xFFFFFFFFull), m, 64);
    int hi = __shfl_xor((int)(unsigned)(v >> 32), m, 64);
    return ((unsigned long long)(unsigned)hi << 32) | (unsigned long long)(unsigned)lo;
}

// ---------------------------------------------------------------------------
// Per-batch: histogram candidates -> exact top-500 threshold bucket -> filter
// -> bitonic sort 1024 (desc, index-ascending tie-break) -> emit 500 sorted
// pixel indices. All gather-heavy per-keypoint work moved to refine_desc_k
// (this kernel only occupies 8 CUs; keep it minimal).
// ---------------------------------------------------------------------------
__global__ __launch_bounds__(1024) void topk_k(const unsigned* __restrict__ cnt,
                                               const unsigned long long* __restrict__ pool,
                                               unsigned* __restrict__ kbuf) {
    int b = blockIdx.x;
    int tid = threadIdx.x;
    __shared__ unsigned hist[NBINS];
    __shared__ unsigned long long skeys[1024];
    __shared__ int bstar;
    __shared__ unsigned fcnt;

    for (int i = tid; i < NBINS; i += 1024) hist[i] = 0;
    if (tid == 0) fcnt = 0;
    __syncthreads();

    unsigned n = cnt[b];
    if (n > POOLCAP) n = POOLCAP;
    const unsigned long long* pb = pool + (size_t)b * POOLCAP;
    for (unsigned i = tid; i < n; i += 1024) {
        float v = __uint_as_float((unsigned)(pb[i] >> 32));
        atomicAdd(&hist[bucket_of(v)], 1u);
    }
    __syncthreads();
    if (tid == 0) {
        unsigned cum = 0;
        int B = 0;
        for (int bin = NBINS - 1; bin >= 0; --bin) {
            cum += hist[bin];
            if (cum >= TOPK) { B = bin; break; }
        }
        bstar = B;
    }
    __syncthreads();
    int Bs = bstar;
    for (unsigned i = tid; i < n; i += 1024) {
        unsigned long long k = pb[i];
        float v = __uint_as_float((unsigned)(k >> 32));
        if (bucket_of(v) >= Bs) {
            unsigned p = atomicAdd(&fcnt, 1u);
            if (p < 1024) skeys[p] = k;
        }
    }
    __syncthreads();
    unsigned nf = fcnt < 1024u ? fcnt : 1024u;
    unsigned long long key = (tid < (int)nf) ? skeys[tid] : 0ULL;

    // bitonic sort 1024, overall descending
    for (unsigned kk = 2; kk <= 1024; kk <<= 1) {
        for (unsigned j = kk >> 1; j > 0; j >>= 1) {
            unsigned long long partner;
            if (j >= 64) {
                __syncthreads();
                skeys[tid] = key;
                __syncthreads();
                partner = skeys[tid ^ j];
            } else {
                partner = shfl_xor_u64(key, (int)j);
            }
            bool keepMax = (((tid & kk) == 0) == ((tid & j) == 0));
            unsigned long long mx = key > partner ? key : partner;
            unsigned long long mn = key > partner ? partner : key;
            key = keepMax ? mx : mn;
        }
    }

    if (tid < TOPK) {
        unsigned lo = (unsigned)(key & 0xFFFFFFFFull);
        unsigned pix = (key == 0ULL) ? 0u : (0xFFFFFFFFu - lo);
        kbuf[b * TOPK + tid] = pix;
    }
}

// ---------------------------------------------------------------------------
// One wave per keypoint (4 waves/block, 125x8 blocks = 4000 waves): lanes 0-24
// do the 5x5 softmax refinement (butterfly reduce over 32-lane segment),
// lane 0 does the kptscore bilinear + scalar outputs, all 64 lanes do the
// descriptor bilinear gather (lane = channel) + L2 norm.
// ---------------------------------------------------------------------------
__global__ __launch_bounds__(256) void refine_desc_k(const float* __restrict__ sc,
                                                     const float* __restrict__ dm,
                                                     const unsigned* __restrict__ kbuf,
                                                     float* __restrict__ out) {
    int b = blockIdx.y;
    int wave = threadIdx.x >> 6, lane = threadIdx.x & 63;
    int kp = blockIdx.x * 4 + wave;

    unsigned pix = kbuf[b * TOPK + kp];
    int ys = pix / WW, xs = pix - ys * WW;
    const float* sp = sc + (size_t)b * NPIX;

    // --- 5x5 softmax refinement on lanes 0..24 (segment of 32) ---
    int dx = lane % 5 - 2, dy = lane / 5 - 2;
    float v = -INFINITY;
    if (lane < 25) {
        int iy = ys + dy;
        iy = iy < 0 ? 0 : (iy > HH - 1 ? HH - 1 : iy);
        int ix = xs + dx;
        ix = ix < 0 ? 0 : (ix > WW - 1 ? WW - 1 : ix);
        v = sp[iy * WW + ix];
    }
    float mxv = v;
#pragma unroll
    for (int m = 16; m; m >>= 1) mxv = fmaxf(mxv, __shfl_xor(mxv, m, 32));
    float e = (lane < 25) ? expf((v - mxv) * 10.0f) : 0.0f;
    float se = e, sx = e * (float)dx, sy = e * (float)dy;
#pragma unroll
    for (int m = 16; m; m >>= 1) {
        se += __shfl_xor(se, m, 32);
        sx += __shfl_xor(sx, m, 32);
        sy += __shfl_xor(sy, m, 32);
    }
    float invs = 1.0f / (se + 1e-12f);
    float xr = sx * invs, yr = sy * invs;
    float ddx = ((float)dx - xr) * 0.5f;
    float ddy = ((float)dy - yr) * 0.5f;
    float dd = e * (ddx * ddx + ddy * ddy);
#pragma unroll
    for (int m = 16; m; m >>= 1) dd += __shfl_xor(dd, m, 32);
    float disp = dd * invs;

    float kxn = ((float)xs + xr) / 639.0f * 2.0f - 1.0f;
    float kyn = ((float)ys + yr) / 479.0f * 2.0f - 1.0f;
    float px = fminf(fmaxf((kxn + 1.0f) * 0.5f * 639.0f, 0.0f), 639.0f);
    float py = fminf(fmaxf((kyn + 1.0f) * 0.5f * 479.0f, 0.0f), 479.0f);

    if (lane == 0) {
        out[((size_t)b * TOPK + kp) * 2 + 0] = kxn;
        out[((size_t)b * TOPK + kp) * 2 + 1] = kyn;
        int x0 = (int)floorf(px), y0 = (int)floorf(py);
        int x1 = x0 + 1 > WW - 1 ? WW - 1 : x0 + 1;
        int y1 = y0 + 1 > HH - 1 ? HH - 1 : y0 + 1;
        float wx = px - (float)x0, wy = py - (float)y0;
        float v00 = sp[y0 * WW + x0], v01 = sp[y0 * WW + x1];
        float v10 = sp[y1 * WW + x0], v11 = sp[y1 * WW + x1];
        float ks = v00 * (1 - wx) * (1 - wy) + v01 * wx * (1 - wy) +
                   v10 * (1 - wx) * wy + v11 * wx * wy;
        out[264000 + b * TOPK + kp] = ks;
        out[268000 + b * TOPK + kp] = disp;
    }

    // broadcast sampling coords to all 64 lanes (upper half has garbage)
    px = __shfl(px, 0, 64);
    py = __shfl(py, 0, 64);

    // --- descriptor sampling: lane = channel ---
    int x0 = (int)floorf(px), y0 = (int)floorf(py);
    int x1 = x0 + 1 > WW - 1 ? WW - 1 : x0 + 1;
    int y1 = y0 + 1 > HH - 1 ? HH - 1 : y0 + 1;
    float wx = px - (float)x0, wy = py - (float)y0;
    const float* ch = dm + ((size_t)b * 64 + lane) * NPIX;
    float v00 = ch[y0 * WW + x0], v01 = ch[y0 * WW + x1];
    float v10 = ch[y1 * WW + x0], v11 = ch[y1 * WW + x1];
    float d = v00 * (1 - wx) * (1 - wy) + v01 * wx * (1 - wy) +
              v10 * (1 - wx) * wy + v11 * wx * wy;
    float ssq = d * d;
#pragma unroll
    for (int m = 32; m; m >>= 1) ssq += __shfl_xor(ssq, m, 64);
    float inv = 1.0f / fmaxf(sqrtf(ssq), 1e-12f);
    out[8000 + ((size_t)b * TOPK + kp) * 64 + lane] = d * inv;
}

extern "C" void kernel_launch(void* const* d_in, const int* in_sizes, int n_in,
                              void* d_out, int out_size, void* d_ws, size_t ws_size,
                              hipStream_t stream) {
    const float* sc = (const float*)d_in[0];
    const float* dm = (const float*)d_in[1];
    float* out = (float*)d_out;

    char* ws = (char*)d_ws;
    unsigned* cnt = (unsigned*)ws;                               // 8 u32
    unsigned long long* pool = (unsigned long long*)(ws + 64);   // 8 * POOLCAP u64
    unsigned* kbuf = (unsigned*)(ws + 64 + (size_t)BATCH * POOLCAP * 8);  // 8*500 u32

    hipMemsetAsync(cnt, 0, BATCH * sizeof(unsigned), stream);

    dim3 g1(WW / TS, HH / TS, BATCH);
    fused_nms_k<<<g1, 256, 0, stream>>>(sc, cnt, pool);
    topk_k<<<BATCH, 1024, 0, stream>>>(cnt, pool, kbuf);
    dim3 g3(TOPK / 4, BATCH);
    refine_desc_k<<<g3, 256, 0, stream>>>(sc, dm, kbuf, out);
}